// Round 1
// baseline (1393.592 us; speedup 1.0000x reference)
//
#include <hip/hip_runtime.h>

#define FEAT 128

// ---------------- graph-structure kernels ----------------

__global__ void zero_int_kernel(int* __restrict__ p, int n) {
  int i = blockIdx.x * blockDim.x + threadIdx.x;
  if (i < n) p[i] = 0;
}

__global__ void count_deg_kernel(const int* __restrict__ ei, int E, int* __restrict__ cnt) {
  int e = blockIdx.x * blockDim.x + threadIdx.x;
  if (e < E) atomicAdd(&cnt[ei[E + e]], 1);
}

__global__ void dis_kernel(const int* __restrict__ cnt, float* __restrict__ dis, int n) {
  int i = blockIdx.x * blockDim.x + threadIdx.x;
  if (i < n) dis[i] = rsqrtf((float)(cnt[i] + 1));  // +1 self-loop; deg>=1 always
}

// 3-kernel exclusive scan of cnt[0..N) -> row_ptr (1024 elems/block, nb<=256)
__global__ void scan_partials_kernel(const int* __restrict__ cnt, int* __restrict__ bsum, int N) {
  __shared__ int sd[256];
  int t = threadIdx.x;
  int base = blockIdx.x * 1024 + t * 4;
  int s = 0;
#pragma unroll
  for (int u = 0; u < 4; ++u) { int i = base + u; if (i < N) s += cnt[i]; }
  sd[t] = s; __syncthreads();
  for (int o = 128; o > 0; o >>= 1) { if (t < o) sd[t] += sd[t + o]; __syncthreads(); }
  if (t == 0) bsum[blockIdx.x] = sd[0];
}

__global__ void scan_offsets_kernel(const int* __restrict__ bsum, int* __restrict__ boff,
                                    int nb, int* __restrict__ row_ptr, int N, int E) {
  __shared__ int sd[256];
  int t = threadIdx.x;
  int v = (t < nb) ? bsum[t] : 0;
  sd[t] = v; __syncthreads();
  for (int o = 1; o < 256; o <<= 1) {
    int x = (t >= o) ? sd[t - o] : 0;
    __syncthreads();
    sd[t] += x;
    __syncthreads();
  }
  if (t < nb) boff[t] = sd[t] - v;  // exclusive
  if (t == 0) row_ptr[N] = E;
}

__global__ void scan_final_kernel(const int* __restrict__ cnt, const int* __restrict__ boff,
                                  int* __restrict__ row_ptr, int* __restrict__ cursor, int N) {
  __shared__ int sd[256];
  int t = threadIdx.x;
  int base = blockIdx.x * 1024 + t * 4;
  int v[4]; int ts = 0;
#pragma unroll
  for (int u = 0; u < 4; ++u) { int i = base + u; v[u] = (i < N) ? cnt[i] : 0; ts += v[u]; }
  sd[t] = ts; __syncthreads();
  for (int o = 1; o < 256; o <<= 1) {
    int x = (t >= o) ? sd[t - o] : 0;
    __syncthreads();
    sd[t] += x;
    __syncthreads();
  }
  int run = boff[blockIdx.x] + sd[t] - ts;
#pragma unroll
  for (int u = 0; u < 4; ++u) {
    int i = base + u;
    if (i < N) { row_ptr[i] = run; cursor[i] = run; run += v[u]; }
  }
}

__global__ void fill_kernel(const int* __restrict__ ei, int E, int* __restrict__ cursor,
                            int* __restrict__ col) {
  int e = blockIdx.x * blockDim.x + threadIdx.x;
  if (e < E) {
    int d = ei[E + e];
    int pos = atomicAdd(&cursor[d], 1);
    col[pos] = ei[e];
  }
}

// ---------------- dense kernels ----------------

// C[r][0:128] = (A[r][0:128] @ W[128][128]) * scale[r]   (scale==nullptr -> 1)
// 64 rows per 256-thread block; thread owns rows tr*8..tr*8+7, cols tc*4..tc*4+3.
__global__ __launch_bounds__(256) void mm_scale_kernel(
    const float* __restrict__ A, const float* __restrict__ W,
    const float* __restrict__ scale, float* __restrict__ C, int N) {
  __shared__ float Ws[32][128];
  __shared__ float As[32][68];  // transposed A chunk [k][row], stride 68 keeps 16B align + <=2-way banks
  int t = threadIdx.x;
  int tc = t & 31;
  int tr = t >> 5;
  int row0 = blockIdx.x * 64;
  float4 acc[8];
#pragma unroll
  for (int j = 0; j < 8; ++j) acc[j] = make_float4(0.f, 0.f, 0.f, 0.f);

  for (int kk = 0; kk < 128; kk += 32) {
#pragma unroll
    for (int u = 0; u < 4; ++u) {           // W chunk: 32x128 floats
      int idx = t + u * 256;
      int k = idx >> 5;
      int c4 = idx & 31;
      float4 w4 = ((const float4*)(W + (size_t)(kk + k) * 128))[c4];
      *(float4*)&Ws[k][c4 * 4] = w4;
    }
#pragma unroll
    for (int u = 0; u < 2; ++u) {           // A chunk: 64 rows x 32 k, store transposed
      int idx = t + u * 256;
      int r = idx >> 3;
      int k4 = idx & 7;
      int grow = row0 + r;
      float4 a4 = (grow < N) ? ((const float4*)(A + (size_t)grow * 128 + kk))[k4]
                             : make_float4(0.f, 0.f, 0.f, 0.f);
      As[k4 * 4 + 0][r] = a4.x;
      As[k4 * 4 + 1][r] = a4.y;
      As[k4 * 4 + 2][r] = a4.z;
      As[k4 * 4 + 3][r] = a4.w;
    }
    __syncthreads();
#pragma unroll
    for (int k = 0; k < 32; ++k) {
      float4 w = *(const float4*)&Ws[k][tc * 4];
      float4 a0 = *(const float4*)&As[k][tr * 8];
      float4 a1 = *(const float4*)&As[k][tr * 8 + 4];
#define MM_FMA(j, s)                          \
      acc[j].x = fmaf(s, w.x, acc[j].x);      \
      acc[j].y = fmaf(s, w.y, acc[j].y);      \
      acc[j].z = fmaf(s, w.z, acc[j].z);      \
      acc[j].w = fmaf(s, w.w, acc[j].w);
      MM_FMA(0, a0.x) MM_FMA(1, a0.y) MM_FMA(2, a0.z) MM_FMA(3, a0.w)
      MM_FMA(4, a1.x) MM_FMA(5, a1.y) MM_FMA(6, a1.z) MM_FMA(7, a1.w)
#undef MM_FMA
    }
    __syncthreads();
  }
#pragma unroll
  for (int j = 0; j < 8; ++j) {
    int r = row0 + tr * 8 + j;
    if (r < N) {
      float s = scale ? scale[r] : 1.0f;
      float4 o = acc[j];
      o.x *= s; o.y *= s; o.z *= s; o.w *= s;
      ((float4*)(C + (size_t)r * 128))[tc] = o;
    }
  }
}

// out[i] = relu(dis[i] * (sum_{e: dst=i} hs[src_e] + hs[i]) + b)
// one wave per node (4 nodes / 256-thread block), lane holds float2 of features.
__global__ __launch_bounds__(256) void agg_kernel(
    const float* __restrict__ hs, const int* __restrict__ row_ptr,
    const int* __restrict__ col, const float* __restrict__ dis,
    const float* __restrict__ bias, float* __restrict__ out, int N) {
  int node = blockIdx.x * 4 + (threadIdx.x >> 6);
  int lane = threadIdx.x & 63;
  if (node >= N) return;
  const float2* h2 = (const float2*)hs;
  float2 self = h2[(size_t)node * 64 + lane];
  float ax = self.x, ay = self.y;  // self-loop term
  int s = row_ptr[node], e = row_ptr[node + 1];
  int i = s;
  for (; i + 4 <= e; i += 4) {
    int s0 = col[i], s1 = col[i + 1], s2 = col[i + 2], s3 = col[i + 3];
    float2 v0 = h2[(size_t)s0 * 64 + lane];
    float2 v1 = h2[(size_t)s1 * 64 + lane];
    float2 v2 = h2[(size_t)s2 * 64 + lane];
    float2 v3 = h2[(size_t)s3 * 64 + lane];
    ax += (v0.x + v1.x) + (v2.x + v3.x);
    ay += (v0.y + v1.y) + (v2.y + v3.y);
  }
  for (; i < e; ++i) {
    int sc = col[i];
    float2 v = h2[(size_t)sc * 64 + lane];
    ax += v.x; ay += v.y;
  }
  float d = dis[node];
  float2 b2 = ((const float2*)bias)[lane];
  float ox = fmaxf(fmaf(d, ax, b2.x), 0.f);
  float oy = fmaxf(fmaf(d, ay, b2.y), 0.f);
  ((float2*)out)[(size_t)node * 64 + lane] = make_float2(ox, oy);
}

// mean pool per graph; batch is sorted -> binary search boundaries.
__global__ void pool_kernel(const float* __restrict__ h, const int* __restrict__ batch,
                            float* __restrict__ g, int N) {
  int grp = blockIdx.x, t = threadIdx.x;
  int lo = 0, hi = N;
  while (lo < hi) { int m = (lo + hi) >> 1; if (batch[m] < grp) lo = m + 1; else hi = m; }
  int start = lo;
  hi = N;
  while (lo < hi) { int m = (lo + hi) >> 1; if (batch[m] <= grp) lo = m + 1; else hi = m; }
  int end = lo;
  float a0 = 0.f, a1 = 0.f, a2 = 0.f, a3 = 0.f;
  int i = start;
  for (; i + 4 <= end; i += 4) {
    a0 += h[(size_t)i * 128 + t];
    a1 += h[(size_t)(i + 1) * 128 + t];
    a2 += h[(size_t)(i + 2) * 128 + t];
    a3 += h[(size_t)(i + 3) * 128 + t];
  }
  for (; i < end; ++i) a0 += h[(size_t)i * 128 + t];
  float sum = (a0 + a1) + (a2 + a3);
  float cntf = (float)(end - start);
  g[grp * 128 + t] = sum / fmaxf(cntf, 1.0f);
}

__global__ void lin_relu_kernel(const float* __restrict__ g, const float* __restrict__ W,
                                const float* __restrict__ b, float* __restrict__ out) {
  __shared__ float row[128];
  int grp = blockIdx.x, t = threadIdx.x;
  row[t] = g[grp * 128 + t];
  __syncthreads();
  float acc = b[t];
#pragma unroll 8
  for (int k = 0; k < 128; ++k) acc = fmaf(row[k], W[k * 128 + t], acc);
  out[grp * 128 + t] = fmaxf(acc, 0.f);
}

__global__ void lin2_kernel(const float* __restrict__ g1, const float* __restrict__ W,
                            const float* __restrict__ b, float* __restrict__ out, int C) {
  __shared__ float row[128];
  int grp = blockIdx.x, t = threadIdx.x;
  row[t] = g1[grp * 128 + t];
  __syncthreads();
  if (t < C) {
    float acc = b[t];
#pragma unroll 8
    for (int k = 0; k < 128; ++k) acc = fmaf(row[k], W[k * C + t], acc);
    out[grp * C + t] = acc;
  }
}

// ---------------- launch ----------------

extern "C" void kernel_launch(void* const* d_in, const int* in_sizes, int n_in,
                              void* d_out, int out_size, void* d_ws, size_t ws_size,
                              hipStream_t stream) {
  const float* x   = (const float*)d_in[0];
  const int*   ei  = (const int*)d_in[1];     // [2][E]: src row then dst row
  const int*   bat = (const int*)d_in[2];
  const float* W1  = (const float*)d_in[3];
  const float* b1  = (const float*)d_in[4];
  const float* W2  = (const float*)d_in[5];
  const float* b2  = (const float*)d_in[6];
  const float* W3  = (const float*)d_in[7];
  const float* b3  = (const float*)d_in[8];
  const float* l1w = (const float*)d_in[9];
  const float* l1b = (const float*)d_in[10];
  const float* l2w = (const float*)d_in[11];
  const float* l2b = (const float*)d_in[12];

  int N = in_sizes[2];
  int E = in_sizes[1] / 2;
  int C = in_sizes[12];
  int G = out_size / C;
  float* outp = (float*)d_out;

  char* wp = (char*)d_ws;
  auto alloc = [&](size_t bytes) -> void* {
    void* p = (void*)wp;
    wp += (bytes + 255) & ~(size_t)255;
    return p;
  };
  int nb = (N + 1023) / 1024;  // <=256 required by scan_offsets_kernel
  int*   cnt     = (int*)alloc((size_t)N * 4);
  float* dis     = (float*)alloc((size_t)N * 4);
  int*   row_ptr = (int*)alloc((size_t)(N + 1) * 4);
  int*   cursor  = (int*)alloc((size_t)N * 4);
  int*   col     = (int*)alloc((size_t)E * 4);
  int*   bsum    = (int*)alloc((size_t)nb * 4);
  int*   boff    = (int*)alloc((size_t)nb * 4);
  float* bufA    = (float*)alloc((size_t)N * FEAT * 4);
  float* bufB    = (float*)alloc((size_t)N * FEAT * 4);
  float* g       = (float*)alloc((size_t)G * FEAT * 4);
  float* g1      = (float*)alloc((size_t)G * FEAT * 4);

  int nB = (N + 255) / 256;
  int eB = (E + 255) / 256;

  // CSR + norm build (once, reused for all 3 layers)
  zero_int_kernel<<<nB, 256, 0, stream>>>(cnt, N);
  count_deg_kernel<<<eB, 256, 0, stream>>>(ei, E, cnt);
  dis_kernel<<<nB, 256, 0, stream>>>(cnt, dis, N);
  scan_partials_kernel<<<nb, 256, 0, stream>>>(cnt, bsum, N);
  scan_offsets_kernel<<<1, 256, 0, stream>>>(bsum, boff, nb, row_ptr, N, E);
  scan_final_kernel<<<nb, 256, 0, stream>>>(cnt, boff, row_ptr, cursor, N);
  fill_kernel<<<eB, 256, 0, stream>>>(ei, E, cursor, col);

  int mmB = (N + 63) / 64;
  int agB = (N + 3) / 4;

  mm_scale_kernel<<<mmB, 256, 0, stream>>>(x, W1, dis, bufA, N);
  agg_kernel<<<agB, 256, 0, stream>>>(bufA, row_ptr, col, dis, b1, bufB, N);
  mm_scale_kernel<<<mmB, 256, 0, stream>>>(bufB, W2, dis, bufA, N);
  agg_kernel<<<agB, 256, 0, stream>>>(bufA, row_ptr, col, dis, b2, bufB, N);
  mm_scale_kernel<<<mmB, 256, 0, stream>>>(bufB, W3, dis, bufA, N);
  agg_kernel<<<agB, 256, 0, stream>>>(bufA, row_ptr, col, dis, b3, bufB, N);

  pool_kernel<<<G, 128, 0, stream>>>(bufB, bat, g, N);
  lin_relu_kernel<<<G, 128, 0, stream>>>(g, l1w, l1b, g1);
  lin2_kernel<<<G, 128, 0, stream>>>(g1, l2w, l2b, outp, C);
}